// Round 9
// baseline (180.725 us; speedup 1.0000x reference)
//
#include <hip/hip_runtime.h>

#define SEQ   2048
#define BATCH 4
#define DIM   512
#define KBUF  32768
#define VB0   65536
#define P_OFF 131072
#define STAT_OFF 139264
#define LDS_TOTAL 155648
#define NEG_INF  (-__builtin_inff())

typedef short short8 __attribute__((ext_vector_type(8)));
typedef float floatx4 __attribute__((ext_vector_type(4)));

using lds_char = __attribute__((address_space(3))) char;
using g_void   = const __attribute__((address_space(1))) void;
using l_void   = __attribute__((address_space(3))) void;

__device__ __forceinline__ short to_bf16(float x){
    unsigned u = __float_as_uint(x);
    unsigned r = (u + 0x7fffu + ((u >> 16) & 1u)) >> 16;
    return (short)r;
}

__device__ __forceinline__ short8 pack8(floatx4 a, floatx4 b, float s){
    short8 r;
    r[0]=to_bf16(a[0]*s); r[1]=to_bf16(a[1]*s); r[2]=to_bf16(a[2]*s); r[3]=to_bf16(a[3]*s);
    r[4]=to_bf16(b[0]*s); r[5]=to_bf16(b[1]*s); r[6]=to_bf16(b[2]*s); r[7]=to_bf16(b[3]*s);
    return r;
}

// K [k][b][d] fp32 -> Kimg [b][k][d] bf16, per-row 16B-slot XOR swizzle baked in.
extern "C" __global__ void __launch_bounds__(256)
conv_k(const float* __restrict__ K, short* __restrict__ Kimg)
{
    const int t    = blockIdx.x * 256 + threadIdx.x;   // 524288
    const int d8   = t & 63;
    const int row  = t >> 6;                           // k*BATCH + b
    const int k    = row >> 2;
    const int b    = row & 3;
    const float* src = K + (size_t)row * DIM + d8 * 8;
    floatx4 f0 = *(const floatx4*)src;
    floatx4 f1 = *(const floatx4*)(src + 4);
    const int slot = (d8 * 8) ^ ((k & 7) << 3);        // shorts
    *(short8*)(Kimg + ((size_t)b * SEQ + k) * DIM + slot) = pack8(f0, f1, 1.0f);
}

// V [k][b][dv] fp32 -> Vt [b][dv][k] bf16 (transposed, LINEAR — proven).
extern "C" __global__ void __launch_bounds__(256)
conv_v(const float* __restrict__ V, short* __restrict__ Vt)
{
    const int t    = blockIdx.x * 256 + threadIdx.x;   // 524288
    const int dv   = t & 511;
    const int rest = t >> 9;
    const int kc   = rest & 255;
    const int b    = rest >> 8;
    short8 colv;
    #pragma unroll
    for (int i = 0; i < 8; ++i){
        const float f = V[((size_t)(kc*8 + i) * BATCH + b) * DIM + dv];
        colv[i] = to_bf16(f);
    }
    *(short8*)(Vt + ((size_t)b * DIM + dv) * SEQ + kc * 8) = colv;
}

__device__ __forceinline__ void dump_partial(float* ox, float* st,
    const floatx4* oacc, const float* mrow, const float* lrow, int lane)
{
    #pragma unroll
    for (int nt=0; nt<32; ++nt){
        #pragma unroll
        for (int jj=0; jj<4; ++jj) ox[(nt*4 + jj)*64 + lane] = oacc[nt][jj];
    }
    #pragma unroll
    for (int jj=0; jj<4; ++jj){ st[jj*64 + lane] = mrow[jj]; st[(4+jj)*64 + lane] = lrow[jj]; }
}

__device__ __forceinline__ void combine_partial(floatx4* oacc, float* mrow, float* lrow,
    const float* ox, const float* st, int lane)
{
    #pragma unroll
    for (int jj=0; jj<4; ++jj){
        const float m2 = st[jj*64 + lane];
        const float l2 = st[(4+jj)*64 + lane];
        const float M  = fmaxf(mrow[jj], m2);
        const float a1 = (mrow[jj] == NEG_INF) ? 0.f : __expf(mrow[jj] - M);
        const float a2 = (m2       == NEG_INF) ? 0.f : __expf(m2 - M);
        mrow[jj] = M;
        lrow[jj] = a1*lrow[jj] + a2*l2;
        #pragma unroll
        for (int nt=0; nt<32; ++nt)
            oacc[nt][jj] = a1*oacc[nt][jj] + a2*ox[(nt*4 + jj)*64 + lane];
    }
}

extern "C" __global__ void __launch_bounds__(512, 2)
fa_fwd(const float* __restrict__ Qg, const short* __restrict__ Kb,
       const short* __restrict__ Vt, const unsigned char* __restrict__ Mg,
       float* __restrict__ Og)
{
    extern __shared__ __align__(16) char smem[];
    const int tid  = threadIdx.x;
    const int w    = tid >> 6;        // 0..7
    const int lane = tid & 63;
    const int g    = lane >> 4;
    const int c    = lane & 15;
    const int qhalf = w & 1;
    const int par   = w >> 1;         // 4-way kv split (16-row tiles, t == par mod 4)

    // XCD-affine swizzle: batch pinned to an XCD pair for KV L2 locality.
    const int x    = blockIdx.x;
    const int slot = x & 7;
    const int idx  = x >> 3;
    const int b    = slot >> 1;
    const int qt   = idx * 2 + (slot & 1);   // 0..63

    const int q0 = qt * 32 + qhalf * 16;

    char* kbuf = smem + par * 16384;          // K tile [16k][512d] bf16 (swizzled image)
    char* vbuf = smem + VB0 + par * 16384;    // V tile [512dv][16k] bf16 (linear)
    char* Pb   = smem + P_OFF + w * 1024;     // P [16q][32k], upper 16 k always zero

    const short* Kbb = Kb + (size_t)b * SEQ * DIM;
    const short* Vtb = Vt + (size_t)b * DIM * SEQ;

    // ---- Q -> registers (bf16, pre-scaled by 1/sqrt(D)) ----
    const float scale = 0.04419417382415922f;  // 1/sqrt(512)
    short8 qreg[16];
    {
        const float* qrow = Qg + ((size_t)(q0 + c) * BATCH + b) * DIM + g * 8;
        #pragma unroll
        for (int ks = 0; ks < 16; ++ks){
            floatx4 f0 = *(const floatx4*)(qrow + ks*32);
            floatx4 f1 = *(const floatx4*)(qrow + ks*32 + 4);
            qreg[ks] = pack8(f0, f1, scale);
        }
    }

    // ---- zero V buffers (stale-LDS inf/NaN guard) + P upper half ----
    {
        char* vz = smem + VB0 + tid*128;
        floatx4 z4 = {0.f,0.f,0.f,0.f};
        #pragma unroll
        for (int i=0;i<8;++i) *(floatx4*)(vz + i*16) = z4;
        *(float2*)(Pb + (lane>>2)*64 + 32 + (lane&3)*8) = make_float2(0.f, 0.f);
    }

    floatx4 oacc[32];
    #pragma unroll
    for (int i=0;i<32;++i){ floatx4 z = {0.f,0.f,0.f,0.f}; oacc[i]=z; }
    float mrow[4] = {NEG_INF, NEG_INF, NEG_INF, NEG_INF};
    float lrow[4] = {0.f,0.f,0.f,0.f};

    const int ntiles = 2*qt + 2;             // 16-row tiles, uniform across block
    const int iters  = (2*qt + 5) >> 2;

    // wave stages its 8 rows of the parity pair's 16-row K tile (8 KB)
    #define STAGE_K(tt) { \
        const short* ksrc_ = Kbb + ((size_t)((tt)*16 + qhalf*8)) * DIM + lane*8; \
        char* ldst_ = kbuf + qhalf*8192; \
        _Pragma("unroll") \
        for (int i_ = 0; i_ < 8; ++i_) \
            __builtin_amdgcn_global_load_lds((g_void*)(ksrc_ + (size_t)i_*DIM), \
                                             (l_void*)(lds_char*)(ldst_ + i_*1024), 16, 0, 0); }

    // wave stages its 256 dv-rows of the V tile: LDS row dv = 32B ([16k] x 2B),
    // chunk (lane&1) covers k 0..7 / 8..15 -> k-linear rows, no swizzle needed.
    #define STAGE_V(tt) { \
        const short* vsrc_ = Vtb + (size_t)(qhalf*256 + (lane>>1))*SEQ + (tt)*16 + (lane&1)*8; \
        char* ldst_ = vbuf + qhalf*8192; \
        _Pragma("unroll") \
        for (int i_ = 0; i_ < 8; ++i_) \
            __builtin_amdgcn_global_load_lds((g_void*)(vsrc_ + (size_t)i_*32*SEQ), \
                                             (l_void*)(lds_char*)(ldst_ + i_*1024), 16, 0, 0); }

    __syncthreads();   // [Z] zero-init visible before any DMA lands

    if (par < ntiles){ STAGE_K(par); STAGE_V(par); }

    for (int i = 0; i < iters; ++i){
        const int t    = 4*i + par;
        const int kb16 = t * 16;
        const bool active = (t < ntiles);

        __syncthreads();   // [A] K(t),V(t) landed (drains this wave's stages) & visible

        floatx4 sa, sb;
        { floatx4 z = {0.f,0.f,0.f,0.f}; sa=z; sb=z; }
        unsigned char km = 0;
        if (active){
            km = Mg[(kb16 + c) * BATCH + b];
            #pragma unroll
            for (int ks = 0; ks < 16; ks += 2){
                short8 kf0 = *(const short8*)(kbuf + c*1024 +
                               ((ks*64 + g*16) ^ ((c & 7) << 4)));
                short8 kf1 = *(const short8*)(kbuf + c*1024 +
                               (((ks+1)*64 + g*16) ^ ((c & 7) << 4)));
                sa = __builtin_amdgcn_mfma_f32_16x16x32_bf16(qreg[ks],   kf0, sa, 0,0,0);
                sb = __builtin_amdgcn_mfma_f32_16x16x32_bf16(qreg[ks+1], kf1, sb, 0,0,0);
            }
        }

        __syncthreads();   // [B] K reads done (both waves) -> restage K

        if (t + 4 < ntiles) STAGE_K(t + 4);

        if (active){
            // ---- mask + online softmax (C layout: row=g*4+jj, col=c) ----
            float s[4];
            #pragma unroll
            for (int jj = 0; jj < 4; ++jj){
                const int col = kb16 + c;
                const int row = q0 + g*4 + jj;
                const float sv = sa[jj] + sb[jj];
                s[jj] = (col > row || km) ? NEG_INF : sv;
            }
            float pmax[4];
            #pragma unroll
            for (int jj=0;jj<4;++jj) pmax[jj] = s[jj];
            #pragma unroll
            for (int msk=1; msk<16; msk<<=1){
                #pragma unroll
                for (int jj=0;jj<4;++jj)
                    pmax[jj] = fmaxf(pmax[jj], __shfl_xor(pmax[jj], msk, 64));
            }
            const bool okd = (pmax[0] <= mrow[0]+8.f) && (pmax[1] <= mrow[1]+8.f)
                          && (pmax[2] <= mrow[2]+8.f) && (pmax[3] <= mrow[3]+8.f);
            if (!__all(okd)){
                float fsc[4];
                #pragma unroll
                for (int jj=0;jj<4;++jj){
                    const float M = fmaxf(mrow[jj], pmax[jj]);
                    const float f = (mrow[jj] == NEG_INF) ? 0.f : __expf(mrow[jj] - M);
                    mrow[jj] = M; lrow[jj] *= f; fsc[jj] = f;
                }
                #pragma unroll
                for (int nt=0; nt<32; ++nt){
                    #pragma unroll
                    for (int jj=0; jj<4; ++jj) oacc[nt][jj] *= fsc[jj];
                }
            }
            float parr[4], psum[4];
            #pragma unroll
            for (int jj=0; jj<4; ++jj){
                const float sv = s[jj];
                const float e = (sv == NEG_INF) ? 0.f : __expf(sv - mrow[jj]);
                parr[jj] = e; psum[jj] = e;
            }
            #pragma unroll
            for (int msk=1; msk<16; msk<<=1){
                #pragma unroll
                for (int jj=0;jj<4;++jj) psum[jj] += __shfl_xor(psum[jj], msk, 64);
            }
            #pragma unroll
            for (int jj=0;jj<4;++jj) lrow[jj] += psum[jj];

            // ---- P [16q][32k]: write live k=c (upper 16 k stay zero) ----
            #pragma unroll
            for (int jj=0; jj<4; ++jj)
                *(short*)(Pb + (g*4 + jj)*64 + c*2) = to_bf16(parr[jj]);

            // ---- O += P V : A = P (b128, zero-padded k), B = V rows (linear) ----
            const short8 pfrag = *(const short8*)(Pb + c*64 + g*16);
            #pragma unroll
            for (int nt = 0; nt < 32; ++nt){
                const int dv = nt*16 + c;
                const short8 vfr = *(const short8*)(vbuf + dv*32 + g*16);
                oacc[nt] = __builtin_amdgcn_mfma_f32_16x16x32_bf16(pfrag, vfr, oacc[nt], 0,0,0);
            }
        }

        __syncthreads();   // [C] V reads done (both waves) -> restage V

        if (t + 4 < ntiles) STAGE_V(t + 4);
    }
    #undef STAGE_K
    #undef STAGE_V

    // ---- 2-round tree merge of the 4 kv-parity partials (per qhalf) ----
    float* stme = (float*)(smem + STAT_OFF + w * 2048);

    __syncthreads();
    if (par & 1){    // par 1 -> slot qhalf ; par 3 -> slot 2+qhalf
        float* ox = (float*)(smem + ((par >> 1)*2 + qhalf) * KBUF);
        dump_partial(ox, stme, oacc, mrow, lrow, lane);
    }
    __syncthreads();
    if (!(par & 1)){
        const float* ox = (const float*)(smem + ((par >> 1)*2 + qhalf) * KBUF);
        const float* st = (const float*)(smem + STAT_OFF + (w + 2) * 2048);
        combine_partial(oacc, mrow, lrow, ox, st, lane);
    }
    __syncthreads();
    if (par == 2){
        float* ox = (float*)(smem + (2 + qhalf) * KBUF);
        dump_partial(ox, stme, oacc, mrow, lrow, lane);
    }
    __syncthreads();
    if (par == 0){
        const float* ox = (const float*)(smem + (2 + qhalf) * KBUF);
        const float* st = (const float*)(smem + STAT_OFF + (w + 4) * 2048);
        combine_partial(oacc, mrow, lrow, ox, st, lane);
        #pragma unroll
        for (int jj=0; jj<4; ++jj){
            const float inv = 1.0f / lrow[jj];
            float* orow = Og + ((size_t)(q0 + g*4 + jj) * BATCH + b) * DIM + c;
            #pragma unroll
            for (int nt=0; nt<32; ++nt) orow[nt*16] = oacc[nt][jj] * inv;
        }
    }
}

extern "C" void kernel_launch(void* const* d_in, const int* in_sizes, int n_in,
                              void* d_out, int out_size, void* d_ws, size_t ws_size,
                              hipStream_t stream)
{
    const float* Q = (const float*)d_in[0];
    const float* K = (const float*)d_in[1];
    const float* V = (const float*)d_in[2];
    const unsigned char* M = (const unsigned char*)d_in[3];
    float* O = (float*)d_out;
    (void)in_sizes; (void)n_in; (void)out_size; (void)ws_size;

    short* Kb = (short*)d_ws;                               // 8.4 MB swizzled K image
    short* Vt = Kb + (size_t)BATCH * SEQ * DIM;             // 8.4 MB linear V^T image

    conv_k<<<2048, 256, 0, stream>>>(K, Kb);
    conv_v<<<2048, 256, 0, stream>>>(V, Vt);

    hipFuncSetAttribute(reinterpret_cast<const void*>(fa_fwd),
                        hipFuncAttributeMaxDynamicSharedMemorySize, LDS_TOTAL);
    fa_fwd<<<256, 512, LDS_TOTAL, stream>>>(Q, Kb, Vt, M, O);
}